// Round 5
// baseline (253.004 us; speedup 1.0000x reference)
//
#include <hip/hip_runtime.h>
#include <math.h>

#define NN 100000
#define NE 1600000
#define DD 128          // D_IN == D_OUT
#define NB 1563         // 64-node bins: ceil(100000/64)
#define CAP 1280        // per-bin entry capacity; Poisson(1024) max over 1563 bins ~1147
#define PB 196          // partition blocks (8192 edges each, 1024 threads)
#define CB 196          // conv blocks (grid-stride)

// ---------------------------------------------------------------------------
// d_ws layout (int32 units), ~33.7 MB used:
//   Hh      [NN*DD fp16]   @ WS_HH   (25.6 MB)
//   cursor  [NB]           @ WS_CUR  (zeroed via hipMemsetAsync)
//   entries [NB*CAP]       @ WS_ENT  (8.0 MB; packed (src&63)<<17 | dst)
//   Wh      [128*256 fp16] @ WS_WH   (64 KB; W pre-converted in prep)
// ---------------------------------------------------------------------------
#define WS_HH  0
#define WS_CUR 6400000
#define WS_ENT (WS_CUR + NB)
#define WS_WH  (WS_ENT + NB * CAP)

typedef __attribute__((ext_vector_type(8))) _Float16 h8_t;
typedef __attribute__((ext_vector_type(4))) _Float16 h4_t;
typedef __attribute__((ext_vector_type(2))) _Float16 h2_t;
typedef __attribute__((ext_vector_type(4))) float f4_t;

// packed fp32x2 -> fp16x2 (RNE via v_cvt)
__device__ __forceinline__ unsigned pk2h(float x, float y) {
    h2_t h;
    h.x = (_Float16)x;
    h.y = (_Float16)y;
    return *(unsigned*)&h;
}

__device__ __forceinline__ h4_t h4max(h4_t a, h4_t b) {
    return __builtin_elementwise_max(a, b);   // 2x v_pk_max_f16
}

// ---------------------------------------------------------------------------
// Fused prep: blocks [0,PB) partition edges into per-bin regions; blocks
// [PB,PB+CB) convert H fp32 -> fp16 (grid-stride); block PB+CB converts
// W fp32 -> fp16 (64 KB, one block).
// ---------------------------------------------------------------------------
__global__ __launch_bounds__(1024) void prep_kernel(const float* __restrict__ H,
                                                    const int* __restrict__ src,
                                                    const int* __restrict__ dst,
                                                    int* __restrict__ cursor,
                                                    unsigned* __restrict__ entries,
                                                    uint4* __restrict__ Hh4,
                                                    const float* __restrict__ W,
                                                    unsigned* __restrict__ Wh) {
    __shared__ int cnt[NB];    // 6.25 KB
    __shared__ int gcur[NB];   // 6.25 KB
    const int t = threadIdx.x;
    const int b = blockIdx.x;
    if (b < PB) {
        for (int i = t; i < NB; i += 1024) cnt[i] = 0;
        __syncthreads();
        const int base = b * 8192;
        int sv[8];
#pragma unroll
        for (int k = 0; k < 8; ++k) {
            int e = base + k * 1024 + t;
            sv[k] = (e < NE) ? src[e] : -1;
            if (sv[k] >= 0) atomicAdd(&cnt[sv[k] >> 6], 1);
        }
        __syncthreads();
        for (int i = t; i < NB; i += 1024) {
            int c = cnt[i];
            gcur[i] = c ? i * CAP + atomicAdd(&cursor[i], c) : 0;
        }
        __syncthreads();
#pragma unroll
        for (int k = 0; k < 8; ++k) {
            int e = base + k * 1024 + t;
            if (sv[k] >= 0) {
                int s = sv[k];
                int pos = atomicAdd(&gcur[s >> 6], 1);
                entries[pos] = ((unsigned)(s & 63) << 17) | (unsigned)dst[e];
            }
        }
    } else if (b < PB + CB) {
        const int nb = b - PB;
        const int n8 = NN * DD / 8;   // 1.6M tasks of 8 elems
        for (int i = nb * 1024 + t; i < n8; i += CB * 1024) {
            const float4* s = (const float4*)H + (size_t)i * 2;
            float4 a = s[0], c4 = s[1];
            uint4 o;
            o.x = pk2h(a.x, a.y);
            o.y = pk2h(a.z, a.w);
            o.z = pk2h(c4.x, c4.y);
            o.w = pk2h(c4.z, c4.w);
            Hh4[i] = o;
        }
    } else {
        // W fp32 [128][256] -> fp16, 16384 uint outputs over 1024 threads
        for (int i = t; i < 128 * 256 / 2; i += 1024)
            Wh[i] = pk2h(W[2 * i], W[2 * i + 1]);
    }
}

// ---------------------------------------------------------------------------
// Fused agg + matmul. Per 64-node bin:
//   phase 1: counting-sort entries by local node (LDS, atomic-free output)
//   phase 2: gather-max (h4 per 32-lane half, 8 rows in flight/wave) writing
//            the A-tile into LDS X[.][128..256); stage own 64 Hh rows into
//            X[.][0..128)
//   phase 3: [64][256] X-tile  @ Wh^T -> out rows (owned exclusively), fp32.
// MFMA work of co-resident blocks overlaps neighbors' miss-bound gathers.
// LDS ~53 KB -> 3 blocks/CU (12 waves). raw/sorted union with Ws (dead after
// gather). Frag layouts (m89/m91): A[m=lane&15][k=quad*8+j], B[k][n=lane&15],
// C/D row=quad*4+reg, col=lane&15.
// ---------------------------------------------------------------------------
#define XP 72     // Ws row pitch (fp16): 144B -> 2-way bank alias (free)
#define X64P 264  // X row pitch (fp16): 528B -> 2-way bank alias (free)
__global__ __launch_bounds__(256) void aggmat_kernel(
        const unsigned short* __restrict__ Hh,   // [NN][128] fp16
        const int* __restrict__ cursor,
        const unsigned* __restrict__ entries,
        const unsigned short* __restrict__ Wh,   // [128][256] fp16
        const float* __restrict__ bias,          // [128]
        float* __restrict__ out) {               // [NN][128] fp32
    __shared__ __align__(16) unsigned short Xs[64 * X64P];   // 33.8 KB
    __shared__ __align__(16) union SU {
        struct { unsigned raw[CAP]; unsigned sorted[CAP]; } s;   // 10.2 KB
        unsigned short Ws[128 * XP];                             // 18.4 KB
    } u;
    __shared__ int cnt[64], base_s[64], cur[64];
    const int t = threadIdx.x;
    const int b = blockIdx.x;
    const int n = cursor[b];

    // ---- phase 1: counting sort ----
    if (t < 64) cnt[t] = 0;
    __syncthreads();
    for (int i = t; i < n; i += 256) {
        unsigned e = entries[b * CAP + i];
        u.s.raw[i] = e;
        atomicAdd(&cnt[e >> 17], 1);
    }
    __syncthreads();
    if (t < 64) {   // threads 0..63 == wave 0
        int v = cnt[t];
        int incl = v;
#pragma unroll
        for (int o = 1; o < 64; o <<= 1) {
            int y = __shfl_up(incl, o, 64);
            if (t >= o) incl += y;
        }
        base_s[t] = incl - v;
        cur[t] = incl - v;
    }
    __syncthreads();
    for (int i = t; i < n; i += 256) {
        unsigned e = u.s.raw[i];
        int pos = atomicAdd(&cur[e >> 17], 1);
        u.s.sorted[pos] = e & 0x1FFFFu;
    }
    __syncthreads();

    // ---- phase 2a: stage own Hh rows into X[.][0..128) ----
    {
        const int seg = t & 15, r0 = t >> 4;
#pragma unroll
        for (int j = 0; j < 4; ++j) {
            int r = r0 + 16 * j;
            int row = b * 64 + r;
            uint4 v = make_uint4(0, 0, 0, 0);
            if (row < NN) v = *(const uint4*)(Hh + (size_t)row * DD + seg * 8);
            *(uint4*)&Xs[r * X64P + seg * 8] = v;
        }
    }

    // ---- phase 2b: gather-max, A-tile into X[.][128..256) ----
    const int lane = t & 63;
    const int w = t >> 6;
    const int half = lane >> 5;        // 0/1: even/odd neighbor indices
    const int l32 = lane & 31;
    const _Float16* __restrict__ colbase = (const _Float16*)Hh + l32 * 4;
#pragma unroll
    for (int q = 0; q < 16; ++q) {
        int ln = w * 16 + q;
        int s0 = base_s[ln];
        int e0 = s0 + cnt[ln];
        unsigned long long mu = 0xFC00FC00FC00FC00ull;   // 4x -inf fp16
        h4_t m = *(h4_t*)&mu;
        int j = s0 + half;
        for (; j + 6 < e0; j += 8) {                     // 4 rows in flight/half
            int d0 = u.s.sorted[j], d1 = u.s.sorted[j + 2];
            int d2 = u.s.sorted[j + 4], d3 = u.s.sorted[j + 6];
            h4_t v0 = *(const h4_t*)(colbase + (size_t)d0 * DD);
            h4_t v1 = *(const h4_t*)(colbase + (size_t)d1 * DD);
            h4_t v2 = *(const h4_t*)(colbase + (size_t)d2 * DD);
            h4_t v3 = *(const h4_t*)(colbase + (size_t)d3 * DD);
            m = h4max(m, h4max(h4max(v0, v1), h4max(v2, v3)));
        }
        for (; j < e0; j += 2) {
            h4_t v0 = *(const h4_t*)(colbase + (size_t)u.s.sorted[j] * DD);
            m = h4max(m, v0);
        }
        // combine halves: each lane gets partner lane^32's partial max
        uint2 mv = *(uint2*)&m;
        uint2 ov;
        ov.x = (unsigned)__shfl_xor((int)mv.x, 32, 64);
        ov.y = (unsigned)__shfl_xor((int)mv.y, 32, 64);
        h4_t om = *(h4_t*)&ov;
        m = h4max(m, om);
        if (half == 0) {
            uint2 outv = make_uint2(0u, 0u);
            if (s0 < e0) outv = *(uint2*)&m;
            *(uint2*)&Xs[ln * X64P + 128 + l32 * 4] = outv;
        }
    }
    __syncthreads();   // X complete; sorted dead -> Ws may overwrite

    // ---- phase 3: X[64][256] @ Wh[128][256]^T, wave w owns rows w*16..+15 ----
    const int quad = lane >> 4;
    const int l16 = lane & 15;
    f4_t acc[8] = {};
    for (int c = 0; c < 4; ++c) {
        {
            const int seg = t & 7, o0 = t >> 3;
#pragma unroll
            for (int j = 0; j < 4; ++j) {
                int o = o0 + 32 * j;
                uint4 v = *(const uint4*)(Wh + (size_t)o * 256 + c * 64 + seg * 8);
                *(uint4*)&u.Ws[o * XP + seg * 8] = v;
            }
        }
        __syncthreads();
#pragma unroll
        for (int kk = 0; kk < 64; kk += 32) {
            h8_t a = *(const h8_t*)&Xs[(w * 16 + l16) * X64P + c * 64 + kk + quad * 8];
#pragma unroll
            for (int ot = 0; ot < 8; ++ot) {
                h8_t bf = *(const h8_t*)&u.Ws[(ot * 16 + l16) * XP + kk + quad * 8];
                acc[ot] = __builtin_amdgcn_mfma_f32_16x16x32_f16(a, bf, acc[ot], 0, 0, 0);
            }
        }
        __syncthreads();
    }

#pragma unroll
    for (int ot = 0; ot < 8; ++ot) {
        float bv = bias[ot * 16 + l16];
#pragma unroll
        for (int reg = 0; reg < 4; ++reg) {
            int row = b * 64 + w * 16 + quad * 4 + reg;
            if (row < NN)
                out[(size_t)row * DD + ot * 16 + l16] = acc[ot][reg] + bv;
        }
    }
}

extern "C" void kernel_launch(void* const* d_in, const int* in_sizes, int n_in,
                              void* d_out, int out_size, void* d_ws, size_t ws_size,
                              hipStream_t stream) {
    const float* H   = (const float*)d_in[0];
    const int*   src = (const int*)d_in[1];
    const int*   dst = (const int*)d_in[2];
    const float* W   = (const float*)d_in[3];
    const float* b   = (const float*)d_in[4];
    float* out = (float*)d_out;

    int* ws = (int*)d_ws;
    unsigned short* Hh      = (unsigned short*)(ws + WS_HH);
    int*            cursor  = ws + WS_CUR;
    unsigned*       entries = (unsigned*)(ws + WS_ENT);
    unsigned*       Wh      = (unsigned*)(ws + WS_WH);

    hipMemsetAsync(cursor, 0, NB * sizeof(int), stream);
    prep_kernel<<<PB + CB + 1, 1024, 0, stream>>>(H, src, dst, cursor, entries,
                                                  (uint4*)Hh, W, Wh);
    aggmat_kernel<<<NB, 256, 0, stream>>>(
        (const unsigned short*)Hh, cursor, entries,
        (const unsigned short*)Wh, b, out);
}